// Round 15
// baseline (191.365 us; speedup 1.0000x reference)
//
#include <hip/hip_runtime.h>
#include <hip/hip_bf16.h>
#include <math.h>

#define L_    8
#define J_    3
#define N_    2000
#define E_    32000
#define R_    64
#define HID_  1024
#define G_    128
#define H_    8
#define DH_   16
#define P_    10
#define KV_   8
#define OUT2_ 512
#define B_    16
#define ROWS_ 2064   // N_ + R_
#define CAP_  64     // bucket CSR capacity per node
#define GB_   1032   // GEMM blocks: 129 rowgroups (M=16) x 8 layers

typedef float f32x4 __attribute__((ext_vector_type(4)));
typedef short s16x8 __attribute__((ext_vector_type(8)));

__device__ __forceinline__ void cvt_split1(float v, short& h, short& l) {
    unsigned u = __float_as_uint(v);
    h = (short)(u >> 16);
    float rem = v - __uint_as_float(u & 0xffff0000u);
    l = (short)(__float_as_uint(rem) >> 16);
}

__device__ __forceinline__ void cvt_split8(const float* v, s16x8& h, s16x8& l) {
    #pragma unroll
    for (int i = 0; i < 8; ++i) {
        unsigned u = __float_as_uint(v[i]);
        h[i] = (short)(u >> 16);
        float rem = v[i] - __uint_as_float(u & 0xffff0000u);
        l[i] = (short)(__float_as_uint(rem) >> 16);
    }
}

__device__ __forceinline__ void cvt_split8v(float4 a, float4 b, s16x8& h, s16x8& l) {
    short hh, ll;
    cvt_split1(a.x, hh, ll); h[0] = hh; l[0] = ll;
    cvt_split1(a.y, hh, ll); h[1] = hh; l[1] = ll;
    cvt_split1(a.z, hh, ll); h[2] = hh; l[2] = ll;
    cvt_split1(a.w, hh, ll); h[3] = hh; l[3] = ll;
    cvt_split1(b.x, hh, ll); h[4] = hh; l[4] = ll;
    cvt_split1(b.y, hh, ll); h[5] = hh; l[5] = ll;
    cvt_split1(b.z, hh, ll); h[6] = hh; l[6] = ll;
    cvt_split1(b.w, hh, ll); h[7] = hh; l[7] = ll;
}

// ================= 128-thread device bodies (run as k_pre3 tail blocks) =================

// bucket-CSR place: no deg pass, no scan. cur[n] ends as the degree.
__device__ __forceinline__ void place_body(int b, const int* __restrict__ dst,
                                           const int* __restrict__ src,
                                           const int* __restrict__ lab,
                                           int* __restrict__ cur,
                                           int2* __restrict__ sl) {
    int e = b * 128 + threadIdx.x;
    if (e < E_) {
        int n = dst[e];
        int slot = atomicAdd(&cur[n], 1);
        sl[n * CAP_ + slot] = make_int2(src[e], lab[e]);
    }
}

// 128-thread top-k (same (v,i) tie-break as 256-thread original)
__device__ __forceinline__ void topk_body(const float* __restrict__ imp,
                                          int* __restrict__ idx_out, char* pool) {
    float* sv = (float*)pool;            // 8000 B
    float* rv = (float*)(pool + 8192);   // 512 B
    int*   ri = (int*)(pool + 8704);     // 512 B
    int t = threadIdx.x;
    for (int i = t; i < N_; i += 128) sv[i] = imp[i];
    __syncthreads();
    for (int k = 0; k < P_; ++k) {
        float bv = -INFINITY; int bi = N_;
        for (int i = t; i < N_; i += 128) {
            float v = sv[i];
            if (v > bv || (v == bv && i < bi)) { bv = v; bi = i; }
        }
        rv[t] = bv; ri[t] = bi;
        __syncthreads();
        for (int s = 64; s > 0; s >>= 1) {
            if (t < s) {
                float v = rv[t + s]; int i2 = ri[t + s];
                if (v > rv[t] || (v == rv[t] && i2 < ri[t])) { rv[t] = v; ri[t] = i2; }
            }
            __syncthreads();
        }
        if (t == 0) { idx_out[k] = ri[0]; sv[ri[0]] = -INFINITY; }
        __syncthreads();
    }
}

// pre-split path_w Wp1/Wp3 chunks (128-thread: khalf loop)
__device__ __forceinline__ void psplit_body(int l, int j, int halfc, int st,
                                            const float* __restrict__ path_w,
                                            short* __restrict__ Ppk) {
    int lj = l * J_ + j;
    int col = threadIdx.x;               // 0..127
    int c0 = halfc ? 256 : 0;
    size_t base = (((size_t)lj * 2 + halfc) * 4 + st) * 2;
    #pragma unroll
    for (int khalf = 0; khalf < 2; ++khalf) {
        const float* src = path_w + (size_t)lj * 384 * G_
                         + (size_t)(c0 + st * 32 + khalf * 16) * G_ + col;
        short* dh = Ppk + (base + 0) * 4096 + (khalf * 128 + col) * 16;
        short* dl = Ppk + (base + 1) * 4096 + (khalf * 128 + col) * 16;
        #pragma unroll
        for (int kk = 0; kk < 16; ++kk) {
            short h, l2;
            cvt_split1(src[(size_t)kk * G_], h, l2);
            dh[kk] = h; dl[kk] = l2;
        }
    }
}

// attn-weight prep, quarter-split, 128 threads (2 items each)
__device__ __forceinline__ void prep_body(int combo, int q,
                                          const float* __restrict__ path_w,
                                          const float* __restrict__ path_b,
                                          const float* __restrict__ attn1_w,
                                          const float* __restrict__ attn2_p,
                                          float* __restrict__ wPR,
                                          short* __restrict__ PPk,
                                          float* __restrict__ bA) {
    int j = combo / L_;
    int l = combo % L_;
    int t = threadIdx.x;
    size_t wb = (size_t)((l * J_ + j) * 384) * G_;
    size_t ob = (size_t)(j * L_ + l);
    const float* a2 = attn2_p + (size_t)(l * J_ + j) * G_;
    short* pph = PPk + (ob * 2 + 0) * 2048;
    short* ppl = PPk + (ob * 2 + 1) * 2048;
    #pragma unroll
    for (int h2 = 0; h2 < 2; ++h2) {
        int i = q * 256 + h2 * 128 + t;
        int k = i >> 3, h = i & 7;
        const float* a2h = a2 + h * DH_;
        float s1 = 0.f, s2 = 0.f, s3 = 0.f;
        for (int d = 0; d < DH_; ++d) {
            float av = a2h[d];
            int c = h * DH_ + d;
            s1 += path_w[wb + (size_t)k * G_ + c] * av;
            s3 += path_w[wb + (size_t)(128 + k) * G_ + c] * av;
            s2 += path_w[wb + (size_t)(256 + k) * G_ + c] * av;
        }
        s1 += attn1_w[((size_t)(l * J_ + j) * G_ + k) * H_ + h];
        short h1, l1, hh2, l2;
        cvt_split1(s1, h1, l1);
        cvt_split1(s2, hh2, l2);
        pph[h * 128 + k] = h1;        ppl[h * 128 + k] = l1;
        pph[(8 + h) * 128 + k] = hh2; ppl[(8 + h) * 128 + k] = l2;
        wPR[ob * H_ * G_ + h * G_ + k] = s3;
    }
    if (q == 0 && t < H_) {
        float s = 0.f;
        const float* a2h = a2 + t * DH_;
        const float* pb = path_b + (size_t)(l * J_ + j) * G_ + t * DH_;
        for (int d = 0; d < DH_; ++d) s += pb[d] * a2h[d];
        bA[ob * H_ + t] = s;
    }
}

// ================= k_pre0: tg_w repack (k_pre3's only dependency) + cur zero =================
__global__ __launch_bounds__(256) void k_pre0(
    const float* __restrict__ tg_w, short* __restrict__ WpkB,
    int* __restrict__ cur) {
    int b = blockIdx.x;
    if (b == 256) {
        for (int i = threadIdx.x; i < N_; i += 256) cur[i] = 0;
        return;
    }
    int layer = b & 7, gst = b >> 3;
    int tid = threadIdx.x;
    int col = tid & 127, khalf = tid >> 7;
    const float* src = tg_w + ((size_t)layer * HID_ + gst * 32 + khalf * 16) * G_ + col;
    short* dh = WpkB + ((size_t)(layer * 32 + gst) * 2 + 0) * 4096 + col * 32 + khalf * 16;
    short* dl = WpkB + ((size_t)(layer * 32 + gst) * 2 + 1) * 4096 + col * 32 + khalf * 16;
    #pragma unroll
    for (int kk = 0; kk < 16; ++kk) {
        short h, l;
        cvt_split1(src[(size_t)kk * G_], h, l);
        dh[kk] = h; dl[kk] = l;
    }
}

// ---------- pipelined MFMA GEMM, M=16 tiles (2x GEMM block parallelism) + tail ----------
// blocks 0..1031: GEMM: 16 rows x 128 cols, full K=1024, 2 waves split N.
//   Same verified TGITER pipeline as R9/R14; per wave per stage: 1 gload_lds
//   (1KB) + 8 B-loads; tri-buffered 6KB LDS; steady vmcnt(9) keeps
//   {B(st+1):8, A(st+2):1} in flight, retires A(st)+B(st).
// blocks 1032..1570: place(250) | topk(1) | psplit(192) | prep(96) on idle CUs.
__global__ __launch_bounds__(128, 4) void k_pre3(
    const float* __restrict__ nft, const float* __restrict__ rft,
    const short* __restrict__ WpkB, const float* __restrict__ tg_b,
    float* __restrict__ x0, float* __restrict__ rel,
    const int* __restrict__ edst, const int* __restrict__ esrc,
    const int* __restrict__ elab, const float* __restrict__ imp,
    const float* __restrict__ path_w, const float* __restrict__ path_b,
    const float* __restrict__ attn1_w, const float* __restrict__ attn2_p,
    int* __restrict__ cur, int2* __restrict__ csr_sl, int* __restrict__ imp_idx,
    short* __restrict__ Ppk, float* __restrict__ wPR,
    short* __restrict__ PPk, float* __restrict__ bA) {
    __shared__ alignas(16) char POOL3[12288];   // GEMM A-bufs (6KB) / topk scratch (9.2KB)
    int b = blockIdx.x;
    if (b >= GB_) {
        int w = b - GB_;
        if (w < 250) { place_body(w, edst, esrc, elab, cur, csr_sl); return; }
        if (w == 250) { topk_body(imp, imp_idx, POOL3); return; }
        if (w < 443) {
            int v = w - 251;
            int l = v & 7, m = v >> 3;
            int j = m % 3, hs = m / 3;
            psplit_body(l, j, hs >> 2, hs & 3, path_w, Ppk);
            return;
        }
        {
            int v = w - 443;          // 0..95
            prep_body(v >> 2, v & 3, path_w, path_b, attn1_w, attn2_p, wPR, PPk, bA);
            return;
        }
    }

    const int layer = b & 7;           // XCD <-> layer L2 affinity
    const int rg = b >> 3;             // 0..128
    const int row0 = rg * 16;
    const int tid = threadIdx.x;
    const int lane = tid & 63, wv = tid >> 6;
    const int lr = lane & 15, kg = lane >> 4;

    char* ldsb = POOL3;

    // one A source per wave: 8 rows (wv*8 + lane>>3), swizzled k-chunk.
    // LDS row r lives at r*128 within each 2KB buffer (same layout law as R9).
    const float* gsrc0;
    {
        int swz = ((lane & 7) ^ (lane >> 3)) << 2;   // floats
        int rb = row0 + wv * 8 + (lane >> 3);
        if (rb > ROWS_ - 1) rb = ROWS_ - 1;
        gsrc0 = ((rb < N_) ? nft + ((size_t)layer * N_ + rb) * HID_
                           : rft + ((size_t)layer * R_ + (rb - N_)) * HID_) + swz;
    }
    const short* WB = WpkB + (size_t)layer * 262144 + ((wv * 64 + lr) * 32 + kg * 8);

    f32x4 zero = {0.f, 0.f, 0.f, 0.f};
    f32x4 acc4[4];
    #pragma unroll
    for (int n = 0; n < 4; ++n) acc4[n] = zero;

    s16x8 bs[2][4][2];   // [slot][ncolgroup][hi/lo] — all literal-indexed

#define LDA(WR, GST) do { \
    char* lb_ = ldsb + (WR) * 2048 + wv * 1024; \
    __builtin_amdgcn_global_load_lds( \
        (const __attribute__((address_space(1))) void*)(gsrc0 + (GST) * 32), \
        (__attribute__((address_space(3))) void*)(lb_), 16, 0, 0); \
} while (0)

#define LDB(SL, GST) do { \
    const short* bp_ = WB + (size_t)(GST) * 8192; \
    _Pragma("unroll") \
    for (int n_ = 0; n_ < 4; ++n_) { \
        bs[SL][n_][0] = *(const s16x8*)(bp_ + n_ * 512); \
        bs[SL][n_][1] = *(const s16x8*)(bp_ + n_ * 512 + 4096); \
    } \
} while (0)

#define COMP(CUR, SL) do { \
    const int o1_ = (kg * 32) ^ ((lr & 7) << 4); \
    const char* ap_ = ldsb + (CUR) * 2048 + lr * 128; \
    float4 av0_ = *(const float4*)(ap_ + o1_); \
    float4 av1_ = *(const float4*)(ap_ + (o1_ ^ 16)); \
    s16x8 ah_, al_; \
    cvt_split8v(av0_, av1_, ah_, al_); \
    _Pragma("unroll") \
    for (int n_ = 0; n_ < 4; ++n_) { \
        acc4[n_] = __builtin_amdgcn_mfma_f32_16x16x32_bf16(ah_, bs[SL][n_][0], acc4[n_], 0, 0, 0); \
        acc4[n_] = __builtin_amdgcn_mfma_f32_16x16x32_bf16(ah_, bs[SL][n_][1], acc4[n_], 0, 0, 0); \
        acc4[n_] = __builtin_amdgcn_mfma_f32_16x16x32_bf16(al_, bs[SL][n_][0], acc4[n_], 0, 0, 0); \
    } \
} while (0)

// per-wave steady state: issue 8 B-loads + 1 gload_lds, then vmcnt(9)
// (FIFO: retires A(st)+B(st) [+already-done A(st+1) at st=0], keeps
//  {B(st+1):8, A(st+2):1} in flight).
#define TGITER(ST, CUR, WR, SL, SLN) do { \
    LDB(SLN, (ST) + 1); \
    LDA(WR, (ST) + 2); \
    asm volatile("s_waitcnt vmcnt(9)" ::: "memory"); \
    __builtin_amdgcn_s_barrier(); \
    COMP(CUR, SL); \
    __builtin_amdgcn_s_barrier(); \
} while (0)

    // prologue: A 2-stage lead, B 1-stage lead
    LDA(0, 0);
    LDA(1, 1);
    LDB(0, 0);
    for (int st = 0; st < 30; st += 6) {
        TGITER(st + 0, 0, 2, 0, 1);
        TGITER(st + 1, 1, 0, 1, 0);
        TGITER(st + 2, 2, 1, 0, 1);
        TGITER(st + 3, 0, 2, 1, 0);
        TGITER(st + 4, 1, 0, 0, 1);
        TGITER(st + 5, 2, 1, 1, 0);
    }
    // st = 30: pending {B30:8, A31:1}; +LDB(31):8 -> vmcnt(9) retires B30
    LDB(1, 31);
    asm volatile("s_waitcnt vmcnt(9)" ::: "memory");
    __builtin_amdgcn_s_barrier();
    COMP(0, 0);
    // st = 31
    asm volatile("s_waitcnt vmcnt(0)" ::: "memory");
    __builtin_amdgcn_s_barrier();
    COMP(1, 1);
#undef LDA
#undef LDB
#undef COMP
#undef TGITER

    #pragma unroll
    for (int n = 0; n < 4; ++n) {
        int col = wv * 64 + n * 16 + lr;
        float bias = tg_b[layer * G_ + col];
        #pragma unroll
        for (int rgi = 0; rgi < 4; ++rgi) {
            int row = row0 + kg * 4 + rgi;
            if (row >= ROWS_) continue;
            float v = acc4[n][rgi] + bias;
            if (row < N_) x0[((size_t)layer * N_ + row) * G_ + col] = v;
            else          rel[((size_t)layer * R_ + (row - N_)) * G_ + col] = v;
        }
    }
}

// ---------------- Rl = rel@Wp2 + PR epilogue, ALL j (device body) ----------------
__device__ __forceinline__ void rel_body(
    int blk, char* pool,
    const float* __restrict__ rel, const float* __restrict__ path_w,
    const float* __restrict__ wPR, float* __restrict__ Rl, float* __restrict__ PR) {
    float (*At)[132] = (float(*)[132])pool;
    float (*Wt)[132] = (float(*)[132])(pool + 16896);
    const int tid = threadIdx.x;
    const int halfb = blk & 1;
    const int t2 = blk >> 1;
    const int l = t2 % L_;
    const int j = t2 / L_;
    const int row0 = halfb * 32;
    const size_t ob = (size_t)(j * L_ + l);
    {
        int ar = tid >> 3, aq2 = tid & 7;
        const float* asrc = rel + ((size_t)l * R_ + row0 + ar) * G_ + aq2 * 16;
        float4 a0 = ((const float4*)asrc)[0], a1 = ((const float4*)asrc)[1];
        float4 a2 = ((const float4*)asrc)[2], a3 = ((const float4*)asrc)[3];
        *(float4*)&At[ar][aq2 * 16]      = a0;
        *(float4*)&At[ar][aq2 * 16 + 4]  = a1;
        *(float4*)&At[ar][aq2 * 16 + 8]  = a2;
        *(float4*)&At[ar][aq2 * 16 + 12] = a3;
    }
    const size_t wb = (size_t)((l * J_ + j) * 384) * G_;
    const int wrow = tid >> 3, wq = tid & 7;
    float4 rW0, rW1, rW2, rW3;
    auto loadW = [&](int kt) {
        const float* src = path_w + wb + (size_t)(128 + kt * 32 + wrow) * G_ + wq * 16;
        rW0 = ((const float4*)src)[0]; rW1 = ((const float4*)src)[1];
        rW2 = ((const float4*)src)[2]; rW3 = ((const float4*)src)[3];
    };
    const int tr = tid >> 4;
    const int tc = tid & 15;
    float4 acc[2][2];
    acc[0][0] = make_float4(0, 0, 0, 0); acc[0][1] = make_float4(0, 0, 0, 0);
    acc[1][0] = make_float4(0, 0, 0, 0); acc[1][1] = make_float4(0, 0, 0, 0);
    loadW(0);
    for (int wt = 0; wt < 4; ++wt) {
        __syncthreads();
        *(float4*)&Wt[wrow][wq * 16]      = rW0;
        *(float4*)&Wt[wrow][wq * 16 + 4]  = rW1;
        *(float4*)&Wt[wrow][wq * 16 + 8]  = rW2;
        *(float4*)&Wt[wrow][wq * 16 + 12] = rW3;
        __syncthreads();
        if (wt + 1 < 4) loadW(wt + 1);
        #pragma unroll
        for (int kk = 0; kk < 32; ++kk) {
            float4 w0 = *(const float4*)&Wt[kk][tc * 4];
            float4 w1 = *(const float4*)&Wt[kk][64 + tc * 4];
            float a0 = At[tr * 2][wt * 32 + kk];
            float a1 = At[tr * 2 + 1][wt * 32 + kk];
            acc[0][0].x += a0 * w0.x; acc[0][0].y += a0 * w0.y;
            acc[0][0].z += a0 * w0.z; acc[0][0].w += a0 * w0.w;
            acc[0][1].x += a0 * w1.x; acc[0][1].y += a0 * w1.y;
            acc[0][1].z += a0 * w1.z; acc[0][1].w += a0 * w1.w;
            acc[1][0].x += a1 * w0.x; acc[1][0].y += a1 * w0.y;
            acc[1][0].z += a1 * w0.z; acc[1][0].w += a1 * w0.w;
            acc[1][1].x += a1 * w1.x; acc[1][1].y += a1 * w1.y;
            acc[1][1].z += a1 * w1.z; acc[1][1].w += a1 * w1.w;
        }
    }
    #pragma unroll
    for (int r2 = 0; r2 < 2; ++r2) {
        int row = row0 + tr * 2 + r2;
        float* dst = Rl + (ob * R_ + row) * G_;
        *(float4*)(dst + tc * 4) = acc[r2][0];
        *(float4*)(dst + 64 + tc * 4) = acc[r2][1];
    }
    {
        int prow = tid >> 3, ph = tid & 7;
        const float* wp = wPR + (ob * H_ + ph) * G_;
        float s = 0.f;
        for (int k = 0; k < G_; ++k) s += At[prow][k] * wp[k];
        PR[(ob * R_ + row0 + prow) * H_ + ph] = s;
    }
}

// ---------------- MFMA per-j GEMM + fused PS/PDb (half0); j==0 also hosts rel_body ----------------
__global__ __launch_bounds__(256) void k_proj2(
    const float* __restrict__ xcur, const short* __restrict__ Ppk,
    const short* __restrict__ PPkj, const float* __restrict__ bAj,
    const float* __restrict__ path_b, int j,
    float* __restrict__ Xs, float* __restrict__ XdB,
    float* __restrict__ PS, float* __restrict__ PDb,
    const float* __restrict__ rel, const float* __restrict__ path_w,
    const float* __restrict__ wPR, float* __restrict__ Rl, float* __restrict__ PR) {
    __shared__ alignas(16) char POOL[39424];
    if (blockIdx.x >= 512) { rel_body(blockIdx.x - 512, POOL, rel, path_w, wPR, Rl, PR); return; }
    short (*Ah)[40]   = (short(*)[40])(POOL);
    short (*Al)[40]   = (short(*)[40])(POOL + 5120);
    short (*Wh)[40]   = (short(*)[40])(POOL + 10240);
    short (*Wl)[40]   = (short(*)[40])(POOL + 20480);
    short (*PPh)[136] = (short(*)[136])(POOL + 30720);
    short (*PPl)[136] = (short(*)[136])(POOL + 35072);
    const int tid = threadIdx.x;
    const int layer = blockIdx.x & 7;
    const int rest = blockIdx.x >> 3;
    const int halfb = rest & 1;
    const int rg = rest >> 1;          // 0..31
    const int row0 = rg * 64;

    const int arow = tid >> 2, aq = tid & 3;
    int gra = row0 + arow; if (gra >= N_) gra = N_ - 1;
    const float* asrc = xcur + ((size_t)layer * N_ + gra) * G_;
    const int wcol = tid & 127, wkh = tid >> 7;

    const int lane = tid & 63, wv = tid >> 6;
    const int lr = lane & 15, lk = (lane >> 4) * 8;

    if (!halfb) {
        int col = tid >> 4, koff = (tid & 15) * 8;
        s16x8 vh = *(const s16x8*)(PPkj + ((size_t)layer * 2 + 0) * 2048 + tid * 8);
        s16x8 vl = *(const s16x8*)(PPkj + ((size_t)layer * 2 + 1) * 2048 + tid * 8);
        *(s16x8*)&PPh[col][koff] = vh;
        *(s16x8*)&PPl[col][koff] = vl;
    }

    f32x4 zero = {0.f, 0.f, 0.f, 0.f};
    f32x4 acc[4][2];
    f32x4 acc_pp[2];
    #pragma unroll
    for (int i = 0; i < 4; ++i) { acc[i][0] = zero; acc[i][1] = zero; }
    acc_pp[0] = zero; acc_pp[1] = zero;

    float aa[8];
    s16x8 wh0, wh1, wl0, wl1;
    const size_t pbase = (((size_t)(layer * J_ + j) * 2 + halfb) * 4) * 2;
    auto ldG = [&](int st) {
        int kk0 = st * 32;
        *(float4*)&aa[0] = *(const float4*)(asrc + kk0 + aq * 8);
        *(float4*)&aa[4] = *(const float4*)(asrc + kk0 + aq * 8 + 4);
        const s16x8* ph = (const s16x8*)(Ppk + (pbase + (size_t)st * 2 + 0) * 4096 + tid * 16);
        const s16x8* pl = (const s16x8*)(Ppk + (pbase + (size_t)st * 2 + 1) * 4096 + tid * 16);
        wh0 = ph[0]; wh1 = ph[1];
        wl0 = pl[0]; wl1 = pl[1];
    };
    ldG(0);
    for (int st = 0; st < 4; ++st) {
        __syncthreads();
        {
            s16x8 h, l; cvt_split8(aa, h, l);
            *(s16x8*)&Ah[arow][aq * 8] = h;
            *(s16x8*)&Al[arow][aq * 8] = l;
            *(s16x8*)&Wh[wcol][wkh * 16]     = wh0;
            *(s16x8*)&Wh[wcol][wkh * 16 + 8] = wh1;
            *(s16x8*)&Wl[wcol][wkh * 16]     = wl0;
            *(s16x8*)&Wl[wcol][wkh * 16 + 8] = wl1;
        }
        __syncthreads();
        if (st + 1 < 4) ldG(st + 1);
        s16x8 bh[2], bl[2];
        #pragma unroll
        for (int c = 0; c < 2; ++c) {
            int col = wv * 32 + c * 16 + lr;
            bh[c] = *(s16x8*)&Wh[col][lk];
            bl[c] = *(s16x8*)&Wl[col][lk];
        }
        s16x8 ppb_h, ppb_l;
        if (!halfb) {
            ppb_h = *(s16x8*)&PPh[lr][st * 32 + lk];
            ppb_l = *(s16x8*)&PPl[lr][st * 32 + lk];
        }
        #pragma unroll
        for (int mf = 0; mf < 4; ++mf) {
            s16x8 ah = *(s16x8*)&Ah[mf * 16 + lr][lk];
            s16x8 al = *(s16x8*)&Al[mf * 16 + lr][lk];
            #pragma unroll
            for (int c = 0; c < 2; ++c) {
                acc[mf][c] = __builtin_amdgcn_mfma_f32_16x16x32_bf16(ah, bh[c], acc[mf][c], 0, 0, 0);
                acc[mf][c] = __builtin_amdgcn_mfma_f32_16x16x32_bf16(ah, bl[c], acc[mf][c], 0, 0, 0);
                acc[mf][c] = __builtin_amdgcn_mfma_f32_16x16x32_bf16(al, bh[c], acc[mf][c], 0, 0, 0);
            }
            if (!halfb && (mf >> 1) == wv) {
                int i = mf & 1;
                acc_pp[i] = __builtin_amdgcn_mfma_f32_16x16x32_bf16(ah, ppb_h, acc_pp[i], 0, 0, 0);
                acc_pp[i] = __builtin_amdgcn_mfma_f32_16x16x32_bf16(ah, ppb_l, acc_pp[i], 0, 0, 0);
                acc_pp[i] = __builtin_amdgcn_mfma_f32_16x16x32_bf16(al, ppb_h, acc_pp[i], 0, 0, 0);
            }
        }
    }
    const float* pb = path_b + (size_t)(layer * J_ + j) * G_;
    float* outp = halfb ? XdB : Xs;
    const int rbase = (lane >> 4) * 4;
    #pragma unroll
    for (int mf = 0; mf < 4; ++mf) {
        #pragma unroll
        for (int c = 0; c < 2; ++c) {
            int col = wv * 32 + c * 16 + lr;
            float bias = halfb ? pb[col] : 0.f;
            #pragma unroll
            for (int rgi = 0; rgi < 4; ++rgi) {
                int row = row0 + mf * 16 + rbase + rgi;
                if (row < N_) outp[((size_t)layer * N_ + row) * G_ + col] = acc[mf][c][rgi] + bias;
            }
        }
    }
    if (!halfb) {
        #pragma unroll
        for (int i = 0; i < 2; ++i) {
            int mf = wv * 2 + i;
            #pragma unroll
            for (int rgi = 0; rgi < 4; ++rgi) {
                int row = row0 + mf * 16 + rbase + rgi;
                if (row >= N_) continue;
                float val = acc_pp[i][rgi];
                if (lr < 8) PS[((size_t)layer * N_ + row) * H_ + lr] = val;
                else        PDb[((size_t)layer * N_ + row) * H_ + (lr - 8)] = val + bAj[layer * H_ + (lr - 8)];
            }
        }
    }
}

// ---------------- fused per-(layer,node): logits+exp -> single-pass softmax-agg -> residual ----------------
__global__ __launch_bounds__(256) void k_node(
    const float* __restrict__ xcur, const float* __restrict__ Xs,
    const float* __restrict__ XdB, const float* __restrict__ Rlj,
    const float* __restrict__ PS, const float* __restrict__ PDb,
    const float* __restrict__ PRj,
    const int* __restrict__ cnt, const int2* __restrict__ csr_sl,
    float* __restrict__ xnext) {
    int l = blockIdx.x & 7;
    int n = (blockIdx.x >> 3) * 4 + (threadIdx.x >> 6);
    int lane = threadIdx.x & 63;
    int o0 = n * CAP_, o1 = o0 + cnt[n];
    const float* xr = xcur + ((size_t)l * N_ + n) * G_;
    float xv0 = xr[lane], xv1 = xr[lane + 64];
    float xd0 = XdB[((size_t)l * N_ + n) * G_ + lane];
    float xd1 = XdB[((size_t)l * N_ + n) * G_ + lane + 64];
    float out0, out1;
    if (o1 == o0) {
        out0 = fmaxf(xv0, 0.f);
        out1 = fmaxf(xv1, 0.f);
    } else {
        const int h0 = lane >> 4, h1 = h0 + 4;
        const float pd0 = PDb[((size_t)l * N_ + n) * H_ + h0];
        const float pd1 = PDb[((size_t)l * N_ + n) * H_ + h1];
        const float* PSl = PS + (size_t)l * N_ * H_;
        const float* PRl = PRj + (size_t)l * R_ * H_;
        const float* Xsl = Xs + (size_t)l * N_ * G_;
        const float* Rll = Rlj + (size_t)l * R_ * G_;
        float acc0 = 0.f, acc1 = 0.f, sum0 = 0.f, sum1 = 0.f;
        #pragma unroll 2
        for (int k = o0; k < o1; ++k) {
            int2 sl = csr_sl[k];
            float lg0 = PSl[sl.x * H_ + h0] + PRl[sl.y * H_ + h0] + pd0;
            float lg1 = PSl[sl.x * H_ + h1] + PRl[sl.y * H_ + h1] + pd1;
            lg0 = (lg0 >= 0.f) ? lg0 : 0.01f * lg0;
            lg1 = (lg1 >= 0.f) ? lg1 : 0.01f * lg1;
            float e0 = __expf(lg0), e1 = __expf(lg1);
            float v0 = Xsl[(size_t)sl.x * G_ + lane]      + Rll[(size_t)sl.y * G_ + lane];
            float v1 = Xsl[(size_t)sl.x * G_ + lane + 64] + Rll[(size_t)sl.y * G_ + lane + 64];
            acc0 += e0 * v0; sum0 += e0;
            acc1 += e1 * v1; sum1 += e1;
        }
        out0 = fmaxf(acc0 / sum0 + xd0 + xv0, 0.f);
        out1 = fmaxf(acc1 / sum1 + xd1 + xv1, 0.f);
    }
    float* dst = xnext + ((size_t)l * N_ + n) * G_;
    dst[lane] = out0;
    dst[lane + 64] = out1;
}

// ---------------- final: tanh(prefix) @ trans_w + b -> scatter pkv ----------------
// 160 blocks (layer x p x col-half), 1 output col per thread
__global__ __launch_bounds__(256) void k_out(
    const float* __restrict__ xfin, const int* __restrict__ imp_idx,
    const float* __restrict__ trans_w, const float* __restrict__ trans_b,
    float* __restrict__ out) {
    int blk = blockIdx.x;
    int layer = blk / (P_ * 2);
    int rem = blk % (P_ * 2);
    int p = rem >> 1;
    int half = rem & 1;
    __shared__ float th[G_];
    int t = threadIdx.x;
    int row = imp_idx[p];
    if (t < G_) th[t] = tanhf(xfin[((size_t)layer * N_ + row) * G_ + t]);
    __syncthreads();
    int c = half * 256 + t;
    float s = trans_b[layer * OUT2_ + c];
    const float* W = trans_w + (size_t)layer * G_ * OUT2_ + c;
    #pragma unroll 4
    for (int k = 0; k < G_; ++k) s += th[k] * W[(size_t)k * OUT2_];
    int c2 = c >> 8, kv = (c >> 5) & 7, oo = c & 31;
    for (int b = 0; b < B_; ++b) {
        out[(((((size_t)layer * 2 + c2) * B_ + b) * KV_ + kv) * P_ + p) * 32 + oo] = s;
    }
}

extern "C" void kernel_launch(void* const* d_in, const int* in_sizes, int n_in,
                              void* d_out, int out_size, void* d_ws, size_t ws_size,
                              hipStream_t stream) {
    const float* nft     = (const float*)d_in[0];
    const float* rft     = (const float*)d_in[1];
    const float* imp     = (const float*)d_in[2];
    const float* tg_w    = (const float*)d_in[3];
    const float* tg_b    = (const float*)d_in[4];
    const float* path_w  = (const float*)d_in[5];
    const float* path_b  = (const float*)d_in[6];
    const float* attn1_w = (const float*)d_in[7];
    const float* attn2_p = (const float*)d_in[8];
    const float* trans_w = (const float*)d_in[9];
    const float* trans_b = (const float*)d_in[10];
    // d_in[11] lamda: x = s*x + (1-s)*x is a no-op for any s
    const int* esrc = (const int*)d_in[12];
    const int* edst = (const int*)d_in[13];
    const int* elab = (const int*)d_in[14];
    float* out = (float*)d_out;

    char* w = (char*)d_ws;
    size_t off = 0;
    auto alloc = [&](size_t bytes) {
        void* p = w + off;
        off += (bytes + 255) & ~(size_t)255;
        return p;
    };
    float* x0      = (float*)alloc((size_t)L_ * N_ * G_ * 4);
    float* x1      = (float*)alloc((size_t)L_ * N_ * G_ * 4);
    float* rel     = (float*)alloc((size_t)L_ * R_ * G_ * 4);
    float* Xs      = (float*)alloc((size_t)L_ * N_ * G_ * 4);
    float* XdB     = (float*)alloc((size_t)L_ * N_ * G_ * 4);
    float* Rl      = (float*)alloc((size_t)J_ * L_ * R_ * G_ * 4);
    float* PS      = (float*)alloc((size_t)L_ * N_ * H_ * 4);
    float* PDb     = (float*)alloc((size_t)L_ * N_ * H_ * 4);
    float* PR      = (float*)alloc((size_t)J_ * L_ * R_ * H_ * 4);
    float* wPR     = (float*)alloc((size_t)J_ * L_ * H_ * G_ * 4);
    float* bA      = (float*)alloc((size_t)J_ * L_ * H_ * 4);
    short* Wpk     = (short*)alloc((size_t)L_ * 32 * 2 * 4096 * 2);
    short* Ppk     = (short*)alloc((size_t)L_ * J_ * 2 * 4 * 2 * 4096 * 2);
    short* PPk     = (short*)alloc((size_t)J_ * L_ * 2 * 2048 * 2);
    int*   cur     = (int*)alloc(N_ * 4);
    int2*  csr_sl  = (int2*)alloc((size_t)N_ * CAP_ * 8);
    int*   imp_idx = (int*)alloc(P_ * 4);

    // phase 0: tg_w repack (k_pre3's only dependency) + zero cur
    k_pre0<<<257, 256, 0, stream>>>(tg_w, Wpk, cur);
    // phase 1: M=16 pipelined tg GEMM (1032 blocks, 4/CU) || place || topk || psplit || prep
    k_pre3<<<GB_ + 250 + 1 + 192 + 96, 128, 0, stream>>>(
        nft, rft, Wpk, tg_b, x0, rel,
        edst, esrc, elab, imp, path_w, path_b, attn1_w, attn2_p,
        cur, csr_sl, imp_idx, Ppk, wPR, PPk, bA);

    float* xc = x0;
    float* xn = x1;
    for (int j = 0; j < J_; ++j) {
        int grid = (j == 0) ? (512 + J_ * L_ * 2) : 512;
        k_proj2<<<grid, 256, 0, stream>>>(
            xc, Ppk, PPk + (size_t)j * L_ * 2 * 2048, bA + (size_t)j * L_ * H_,
            path_b, j, Xs, XdB, PS, PDb,
            rel, path_w, wPR, Rl, PR);
        k_node<<<L_ * 500, 256, 0, stream>>>(
            xc, Xs, XdB, Rl + (size_t)j * L_ * R_ * G_, PS, PDb,
            PR + (size_t)j * L_ * R_ * H_,
            cur, csr_sl, xn);
        float* tmp = xc; xc = xn; xn = tmp;
    }
    k_out<<<L_ * P_ * 2, 256, 0, stream>>>(xc, imp_idx, trans_w, trans_b, out);
}

// Round 16
// 182.250 us; speedup vs baseline: 1.0500x; 1.0500x over previous
//
#include <hip/hip_runtime.h>
#include <hip/hip_bf16.h>
#include <math.h>

#define L_    8
#define J_    3
#define N_    2000
#define E_    32000
#define R_    64
#define HID_  1024
#define G_    128
#define H_    8
#define DH_   16
#define P_    10
#define KV_   8
#define OUT2_ 512
#define B_    16
#define ROWS_ 2064   // N_ + R_
#define CAP_  64     // bucket CSR capacity per node

typedef float f32x4 __attribute__((ext_vector_type(4)));
typedef short s16x8 __attribute__((ext_vector_type(8)));

__device__ __forceinline__ void cvt_split1(float v, short& h, short& l) {
    unsigned u = __float_as_uint(v);
    h = (short)(u >> 16);
    float rem = v - __uint_as_float(u & 0xffff0000u);
    l = (short)(__float_as_uint(rem) >> 16);
}

__device__ __forceinline__ void cvt_split8(const float* v, s16x8& h, s16x8& l) {
    #pragma unroll
    for (int i = 0; i < 8; ++i) {
        unsigned u = __float_as_uint(v[i]);
        h[i] = (short)(u >> 16);
        float rem = v[i] - __uint_as_float(u & 0xffff0000u);
        l[i] = (short)(__float_as_uint(rem) >> 16);
    }
}

__device__ __forceinline__ void cvt_split8v(float4 a, float4 b, s16x8& h, s16x8& l) {
    short hh, ll;
    cvt_split1(a.x, hh, ll); h[0] = hh; l[0] = ll;
    cvt_split1(a.y, hh, ll); h[1] = hh; l[1] = ll;
    cvt_split1(a.z, hh, ll); h[2] = hh; l[2] = ll;
    cvt_split1(a.w, hh, ll); h[3] = hh; l[3] = ll;
    cvt_split1(b.x, hh, ll); h[4] = hh; l[4] = ll;
    cvt_split1(b.y, hh, ll); h[5] = hh; l[5] = ll;
    cvt_split1(b.z, hh, ll); h[6] = hh; l[6] = ll;
    cvt_split1(b.w, hh, ll); h[7] = hh; l[7] = ll;
}

// ================= 128-thread device bodies (run as k_pre3 tail blocks) =================

// bucket-CSR place: no deg pass, no scan. cur[n] ends as the degree.
__device__ __forceinline__ void place_body(int b, const int* __restrict__ dst,
                                           const int* __restrict__ src,
                                           const int* __restrict__ lab,
                                           int* __restrict__ cur,
                                           int2* __restrict__ sl) {
    int e = b * 128 + threadIdx.x;
    if (e < E_) {
        int n = dst[e];
        int slot = atomicAdd(&cur[n], 1);
        sl[n * CAP_ + slot] = make_int2(src[e], lab[e]);
    }
}

// 128-thread top-k (same (v,i) tie-break as 256-thread original)
__device__ __forceinline__ void topk_body(const float* __restrict__ imp,
                                          int* __restrict__ idx_out, char* pool) {
    float* sv = (float*)pool;            // 8000 B
    float* rv = (float*)(pool + 8192);   // 512 B
    int*   ri = (int*)(pool + 8704);     // 512 B
    int t = threadIdx.x;
    for (int i = t; i < N_; i += 128) sv[i] = imp[i];
    __syncthreads();
    for (int k = 0; k < P_; ++k) {
        float bv = -INFINITY; int bi = N_;
        for (int i = t; i < N_; i += 128) {
            float v = sv[i];
            if (v > bv || (v == bv && i < bi)) { bv = v; bi = i; }
        }
        rv[t] = bv; ri[t] = bi;
        __syncthreads();
        for (int s = 64; s > 0; s >>= 1) {
            if (t < s) {
                float v = rv[t + s]; int i2 = ri[t + s];
                if (v > rv[t] || (v == rv[t] && i2 < ri[t])) { rv[t] = v; ri[t] = i2; }
            }
            __syncthreads();
        }
        if (t == 0) { idx_out[k] = ri[0]; sv[ri[0]] = -INFINITY; }
        __syncthreads();
    }
}

// pre-split path_w Wp1/Wp3 chunks (128-thread: khalf loop)
__device__ __forceinline__ void psplit_body(int l, int j, int halfc, int st,
                                            const float* __restrict__ path_w,
                                            short* __restrict__ Ppk) {
    int lj = l * J_ + j;
    int col = threadIdx.x;               // 0..127
    int c0 = halfc ? 256 : 0;
    size_t base = (((size_t)lj * 2 + halfc) * 4 + st) * 2;
    #pragma unroll
    for (int khalf = 0; khalf < 2; ++khalf) {
        const float* src = path_w + (size_t)lj * 384 * G_
                         + (size_t)(c0 + st * 32 + khalf * 16) * G_ + col;
        short* dh = Ppk + (base + 0) * 4096 + (khalf * 128 + col) * 16;
        short* dl = Ppk + (base + 1) * 4096 + (khalf * 128 + col) * 16;
        #pragma unroll
        for (int kk = 0; kk < 16; ++kk) {
            short h, l2;
            cvt_split1(src[(size_t)kk * G_], h, l2);
            dh[kk] = h; dl[kk] = l2;
        }
    }
}

// attn-weight prep, quarter-split, 128 threads (2 items each)
__device__ __forceinline__ void prep_body(int combo, int q,
                                          const float* __restrict__ path_w,
                                          const float* __restrict__ path_b,
                                          const float* __restrict__ attn1_w,
                                          const float* __restrict__ attn2_p,
                                          float* __restrict__ wPR,
                                          short* __restrict__ PPk,
                                          float* __restrict__ bA) {
    int j = combo / L_;
    int l = combo % L_;
    int t = threadIdx.x;
    size_t wb = (size_t)((l * J_ + j) * 384) * G_;
    size_t ob = (size_t)(j * L_ + l);
    const float* a2 = attn2_p + (size_t)(l * J_ + j) * G_;
    short* pph = PPk + (ob * 2 + 0) * 2048;
    short* ppl = PPk + (ob * 2 + 1) * 2048;
    #pragma unroll
    for (int h2 = 0; h2 < 2; ++h2) {
        int i = q * 256 + h2 * 128 + t;
        int k = i >> 3, h = i & 7;
        const float* a2h = a2 + h * DH_;
        float s1 = 0.f, s2 = 0.f, s3 = 0.f;
        for (int d = 0; d < DH_; ++d) {
            float av = a2h[d];
            int c = h * DH_ + d;
            s1 += path_w[wb + (size_t)k * G_ + c] * av;
            s3 += path_w[wb + (size_t)(128 + k) * G_ + c] * av;
            s2 += path_w[wb + (size_t)(256 + k) * G_ + c] * av;
        }
        s1 += attn1_w[((size_t)(l * J_ + j) * G_ + k) * H_ + h];
        short h1, l1, hh2, l2;
        cvt_split1(s1, h1, l1);
        cvt_split1(s2, hh2, l2);
        pph[h * 128 + k] = h1;        ppl[h * 128 + k] = l1;
        pph[(8 + h) * 128 + k] = hh2; ppl[(8 + h) * 128 + k] = l2;
        wPR[ob * H_ * G_ + h * G_ + k] = s3;
    }
    if (q == 0 && t < H_) {
        float s = 0.f;
        const float* a2h = a2 + t * DH_;
        const float* pb = path_b + (size_t)(l * J_ + j) * G_ + t * DH_;
        for (int d = 0; d < DH_; ++d) s += pb[d] * a2h[d];
        bA[ob * H_ + t] = s;
    }
}

// ================= k_pre0: tg_w repack (k_pre3's only dependency) + cur zero =================
__global__ __launch_bounds__(256) void k_pre0(
    const float* __restrict__ tg_w, short* __restrict__ WpkB,
    int* __restrict__ cur) {
    int b = blockIdx.x;
    if (b == 256) {
        for (int i = threadIdx.x; i < N_; i += 256) cur[i] = 0;
        return;
    }
    int layer = b & 7, gst = b >> 3;
    int tid = threadIdx.x;
    int col = tid & 127, khalf = tid >> 7;
    const float* src = tg_w + ((size_t)layer * HID_ + gst * 32 + khalf * 16) * G_ + col;
    short* dh = WpkB + ((size_t)(layer * 32 + gst) * 2 + 0) * 4096 + col * 32 + khalf * 16;
    short* dl = WpkB + ((size_t)(layer * 32 + gst) * 2 + 1) * 4096 + col * 32 + khalf * 16;
    #pragma unroll
    for (int kk = 0; kk < 16; ++kk) {
        short h, l;
        cvt_split1(src[(size_t)kk * G_], h, l);
        dh[kk] = h; dl[kk] = l;
    }
}

// ---------- pipelined MFMA GEMM (M=32, 520 blocks) + overlapped prep tail ----------
// blocks 0..519: GEMM (M=32 tile, full K=1024, 2 waves split N; gload_lds A,
//   tri-buffered LDS, XOR-swizzled src, counted vmcnt, raw s_barrier).
// blocks 520..1058: place(250) | topk(1) | psplit(192) | prep(96) — these run
//   on the ~90% of CUs the low-occupancy GEMM leaves idle (cost ~0).
__global__ __launch_bounds__(128, 2) void k_pre3(
    const float* __restrict__ nft, const float* __restrict__ rft,
    const short* __restrict__ WpkB, const float* __restrict__ tg_b,
    float* __restrict__ x0, float* __restrict__ rel,
    const int* __restrict__ edst, const int* __restrict__ esrc,
    const int* __restrict__ elab, const float* __restrict__ imp,
    const float* __restrict__ path_w, const float* __restrict__ path_b,
    const float* __restrict__ attn1_w, const float* __restrict__ attn2_p,
    int* __restrict__ cur, int2* __restrict__ csr_sl, int* __restrict__ imp_idx,
    short* __restrict__ Ppk, float* __restrict__ wPR,
    short* __restrict__ PPk, float* __restrict__ bA) {
    __shared__ alignas(16) char POOL3[12288];   // GEMM A-bufs / topk scratch
    int b = blockIdx.x;
    if (b >= 520) {
        int w = b - 520;
        if (w < 250) { place_body(w, edst, esrc, elab, cur, csr_sl); return; }
        if (w == 250) { topk_body(imp, imp_idx, POOL3); return; }
        if (w < 443) {
            int v = w - 251;
            int l = v & 7, m = v >> 3;
            int j = m % 3, hs = m / 3;
            psplit_body(l, j, hs >> 2, hs & 3, path_w, Ppk);
            return;
        }
        {
            int v = w - 443;          // 0..95
            prep_body(v >> 2, v & 3, path_w, path_b, attn1_w, attn2_p, wPR, PPk, bA);
            return;
        }
    }

    const int layer = b & 7;           // XCD <-> layer L2 affinity
    const int rg = b >> 3;             // 0..64
    const int row0 = rg * 32;
    const int tid = threadIdx.x;
    const int lane = tid & 63, wv = tid >> 6;
    const int lr = lane & 15, kg = lane >> 4;

    char* ldsb = POOL3;

    const float* gsrc0;
    const float* gsrc1;
    {
        int swz = ((lane & 7) ^ (lane >> 3)) << 2;   // floats
        int rl0 = wv * 16 + (lane >> 3);
        int rl1 = rl0 + 8;
        int g0 = row0 + rl0; if (g0 > ROWS_ - 1) g0 = ROWS_ - 1;
        int g1 = row0 + rl1; if (g1 > ROWS_ - 1) g1 = ROWS_ - 1;
        gsrc0 = ((g0 < N_) ? nft + ((size_t)layer * N_ + g0) * HID_
                           : rft + ((size_t)layer * R_ + (g0 - N_)) * HID_) + swz;
        gsrc1 = ((g1 < N_) ? nft + ((size_t)layer * N_ + g1) * HID_
                           : rft + ((size_t)layer * R_ + (g1 - N_)) * HID_) + swz;
    }
    const short* WB = WpkB + (size_t)layer * 262144 + ((wv * 64 + lr) * 32 + kg * 8);

    f32x4 zero = {0.f, 0.f, 0.f, 0.f};
    f32x4 acc[2][4];
    #pragma unroll
    for (int i = 0; i < 2; ++i)
        #pragma unroll
        for (int n = 0; n < 4; ++n) acc[i][n] = zero;

    s16x8 bs[2][4][2];   // [slot][ncolgroup][hi/lo] — all literal-indexed

#define LDA(WR, GST) do { \
    char* lb_ = ldsb + (WR) * 4096 + wv * 2048; \
    __builtin_amdgcn_global_load_lds( \
        (const __attribute__((address_space(1))) void*)(gsrc0 + (GST) * 32), \
        (__attribute__((address_space(3))) void*)(lb_), 16, 0, 0); \
    __builtin_amdgcn_global_load_lds( \
        (const __attribute__((address_space(1))) void*)(gsrc1 + (GST) * 32), \
        (__attribute__((address_space(3))) void*)(lb_ + 1024), 16, 0, 0); \
} while (0)

#define LDB(SL, GST) do { \
    const short* bp_ = WB + (size_t)(GST) * 8192; \
    _Pragma("unroll") \
    for (int n_ = 0; n_ < 4; ++n_) { \
        bs[SL][n_][0] = *(const s16x8*)(bp_ + n_ * 512); \
        bs[SL][n_][1] = *(const s16x8*)(bp_ + n_ * 512 + 4096); \
    } \
} while (0)

#define COMP(CUR, SL) do { \
    const int o1_ = (kg * 32) ^ ((lr & 7) << 4); \
    _Pragma("unroll") \
    for (int mf_ = 0; mf_ < 2; ++mf_) { \
        const char* ap_ = ldsb + (CUR) * 4096 + (mf_ * 16 + lr) * 128; \
        float4 av0_ = *(const float4*)(ap_ + o1_); \
        float4 av1_ = *(const float4*)(ap_ + (o1_ ^ 16)); \
        s16x8 ah_, al_; \
        cvt_split8v(av0_, av1_, ah_, al_); \
        _Pragma("unroll") \
        for (int n_ = 0; n_ < 4; ++n_) { \
            acc[mf_][n_] = __builtin_amdgcn_mfma_f32_16x16x32_bf16(ah_, bs[SL][n_][0], acc[mf_][n_], 0, 0, 0); \
            acc[mf_][n_] = __builtin_amdgcn_mfma_f32_16x16x32_bf16(ah_, bs[SL][n_][1], acc[mf_][n_], 0, 0, 0); \
            acc[mf_][n_] = __builtin_amdgcn_mfma_f32_16x16x32_bf16(al_, bs[SL][n_][0], acc[mf_][n_], 0, 0, 0); \
        } \
    } \
} while (0)

// steady state per iter: issue 8 B-loads + 2 gload_lds, then vmcnt(12)
// keeps exactly {gA(st+1), B(st+1), gA(st+2)} in flight, retires A(st)+B(st).
#define TGITER(ST, CUR, WR, SL, SLN) do { \
    LDB(SLN, (ST) + 1); \
    LDA(WR, (ST) + 2); \
    asm volatile("s_waitcnt vmcnt(12)" ::: "memory"); \
    __builtin_amdgcn_s_barrier(); \
    COMP(CUR, SL); \
    __builtin_amdgcn_s_barrier(); \
} while (0)

    // prologue: A 2-stage lead, B 1-stage lead
    LDA(0, 0);
    LDA(1, 1);
    LDB(0, 0);
    for (int st = 0; st < 30; st += 6) {
        TGITER(st + 0, 0, 2, 0, 1);
        TGITER(st + 1, 1, 0, 1, 0);
        TGITER(st + 2, 2, 1, 0, 1);
        TGITER(st + 3, 0, 2, 1, 0);
        TGITER(st + 4, 1, 0, 0, 1);
        TGITER(st + 5, 2, 1, 1, 0);
    }
    // st = 30
    LDB(1, 31);
    asm volatile("s_waitcnt vmcnt(10)" ::: "memory");
    __builtin_amdgcn_s_barrier();
    COMP(0, 0);
    // st = 31
    asm volatile("s_waitcnt vmcnt(0)" ::: "memory");
    __builtin_amdgcn_s_barrier();
    COMP(1, 1);
#undef LDA
#undef LDB
#undef COMP
#undef TGITER

    #pragma unroll
    for (int n = 0; n < 4; ++n) {
        int col = wv * 64 + n * 16 + lr;
        float bias = tg_b[layer * G_ + col];
        #pragma unroll
        for (int mf = 0; mf < 2; ++mf) {
            #pragma unroll
            for (int rgi = 0; rgi < 4; ++rgi) {
                int row = row0 + mf * 16 + kg * 4 + rgi;
                if (row >= ROWS_) continue;
                float v = acc[mf][n][rgi] + bias;
                if (row < N_) x0[((size_t)layer * N_ + row) * G_ + col] = v;
                else          rel[((size_t)layer * R_ + (row - N_)) * G_ + col] = v;
            }
        }
    }
}

// ---------------- Rl = rel@Wp2 + PR epilogue, ALL j (device body) ----------------
__device__ __forceinline__ void rel_body(
    int blk, char* pool,
    const float* __restrict__ rel, const float* __restrict__ path_w,
    const float* __restrict__ wPR, float* __restrict__ Rl, float* __restrict__ PR) {
    float (*At)[132] = (float(*)[132])pool;
    float (*Wt)[132] = (float(*)[132])(pool + 16896);
    const int tid = threadIdx.x;
    const int halfb = blk & 1;
    const int t2 = blk >> 1;
    const int l = t2 % L_;
    const int j = t2 / L_;
    const int row0 = halfb * 32;
    const size_t ob = (size_t)(j * L_ + l);
    {
        int ar = tid >> 3, aq2 = tid & 7;
        const float* asrc = rel + ((size_t)l * R_ + row0 + ar) * G_ + aq2 * 16;
        float4 a0 = ((const float4*)asrc)[0], a1 = ((const float4*)asrc)[1];
        float4 a2 = ((const float4*)asrc)[2], a3 = ((const float4*)asrc)[3];
        *(float4*)&At[ar][aq2 * 16]      = a0;
        *(float4*)&At[ar][aq2 * 16 + 4]  = a1;
        *(float4*)&At[ar][aq2 * 16 + 8]  = a2;
        *(float4*)&At[ar][aq2 * 16 + 12] = a3;
    }
    const size_t wb = (size_t)((l * J_ + j) * 384) * G_;
    const int wrow = tid >> 3, wq = tid & 7;
    float4 rW0, rW1, rW2, rW3;
    auto loadW = [&](int kt) {
        const float* src = path_w + wb + (size_t)(128 + kt * 32 + wrow) * G_ + wq * 16;
        rW0 = ((const float4*)src)[0]; rW1 = ((const float4*)src)[1];
        rW2 = ((const float4*)src)[2]; rW3 = ((const float4*)src)[3];
    };
    const int tr = tid >> 4;
    const int tc = tid & 15;
    float4 acc[2][2];
    acc[0][0] = make_float4(0, 0, 0, 0); acc[0][1] = make_float4(0, 0, 0, 0);
    acc[1][0] = make_float4(0, 0, 0, 0); acc[1][1] = make_float4(0, 0, 0, 0);
    loadW(0);
    for (int wt = 0; wt < 4; ++wt) {
        __syncthreads();
        *(float4*)&Wt[wrow][wq * 16]      = rW0;
        *(float4*)&Wt[wrow][wq * 16 + 4]  = rW1;
        *(float4*)&Wt[wrow][wq * 16 + 8]  = rW2;
        *(float4*)&Wt[wrow][wq * 16 + 12] = rW3;
        __syncthreads();
        if (wt + 1 < 4) loadW(wt + 1);
        #pragma unroll
        for (int kk = 0; kk < 32; ++kk) {
            float4 w0 = *(const float4*)&Wt[kk][tc * 4];
            float4 w1 = *(const float4*)&Wt[kk][64 + tc * 4];
            float a0 = At[tr * 2][wt * 32 + kk];
            float a1 = At[tr * 2 + 1][wt * 32 + kk];
            acc[0][0].x += a0 * w0.x; acc[0][0].y += a0 * w0.y;
            acc[0][0].z += a0 * w0.z; acc[0][0].w += a0 * w0.w;
            acc[0][1].x += a0 * w1.x; acc[0][1].y += a0 * w1.y;
            acc[0][1].z += a0 * w1.z; acc[0][1].w += a0 * w1.w;
            acc[1][0].x += a1 * w0.x; acc[1][0].y += a1 * w0.y;
            acc[1][0].z += a1 * w0.z; acc[1][0].w += a1 * w0.w;
            acc[1][1].x += a1 * w1.x; acc[1][1].y += a1 * w1.y;
            acc[1][1].z += a1 * w1.z; acc[1][1].w += a1 * w1.w;
        }
    }
    #pragma unroll
    for (int r2 = 0; r2 < 2; ++r2) {
        int row = row0 + tr * 2 + r2;
        float* dst = Rl + (ob * R_ + row) * G_;
        *(float4*)(dst + tc * 4) = acc[r2][0];
        *(float4*)(dst + 64 + tc * 4) = acc[r2][1];
    }
    {
        int prow = tid >> 3, ph = tid & 7;
        const float* wp = wPR + (ob * H_ + ph) * G_;
        float s = 0.f;
        for (int k = 0; k < G_; ++k) s += At[prow][k] * wp[k];
        PR[(ob * R_ + row0 + prow) * H_ + ph] = s;
    }
}

// ---------------- MFMA per-j GEMM + fused PS/PDb (half0); j==0 also hosts rel_body ----------------
__global__ __launch_bounds__(256) void k_proj2(
    const float* __restrict__ xcur, const short* __restrict__ Ppk,
    const short* __restrict__ PPkj, const float* __restrict__ bAj,
    const float* __restrict__ path_b, int j,
    float* __restrict__ Xs, float* __restrict__ XdB,
    float* __restrict__ PS, float* __restrict__ PDb,
    const float* __restrict__ rel, const float* __restrict__ path_w,
    const float* __restrict__ wPR, float* __restrict__ Rl, float* __restrict__ PR) {
    __shared__ alignas(16) char POOL[39424];
    if (blockIdx.x >= 512) { rel_body(blockIdx.x - 512, POOL, rel, path_w, wPR, Rl, PR); return; }
    short (*Ah)[40]   = (short(*)[40])(POOL);
    short (*Al)[40]   = (short(*)[40])(POOL + 5120);
    short (*Wh)[40]   = (short(*)[40])(POOL + 10240);
    short (*Wl)[40]   = (short(*)[40])(POOL + 20480);
    short (*PPh)[136] = (short(*)[136])(POOL + 30720);
    short (*PPl)[136] = (short(*)[136])(POOL + 35072);
    const int tid = threadIdx.x;
    const int layer = blockIdx.x & 7;
    const int rest = blockIdx.x >> 3;
    const int halfb = rest & 1;
    const int rg = rest >> 1;          // 0..31
    const int row0 = rg * 64;

    const int arow = tid >> 2, aq = tid & 3;
    int gra = row0 + arow; if (gra >= N_) gra = N_ - 1;
    const float* asrc = xcur + ((size_t)layer * N_ + gra) * G_;
    const int wcol = tid & 127, wkh = tid >> 7;

    const int lane = tid & 63, wv = tid >> 6;
    const int lr = lane & 15, lk = (lane >> 4) * 8;

    if (!halfb) {
        int col = tid >> 4, koff = (tid & 15) * 8;
        s16x8 vh = *(const s16x8*)(PPkj + ((size_t)layer * 2 + 0) * 2048 + tid * 8);
        s16x8 vl = *(const s16x8*)(PPkj + ((size_t)layer * 2 + 1) * 2048 + tid * 8);
        *(s16x8*)&PPh[col][koff] = vh;
        *(s16x8*)&PPl[col][koff] = vl;
    }

    f32x4 zero = {0.f, 0.f, 0.f, 0.f};
    f32x4 acc[4][2];
    f32x4 acc_pp[2];
    #pragma unroll
    for (int i = 0; i < 4; ++i) { acc[i][0] = zero; acc[i][1] = zero; }
    acc_pp[0] = zero; acc_pp[1] = zero;

    float aa[8];
    s16x8 wh0, wh1, wl0, wl1;
    const size_t pbase = (((size_t)(layer * J_ + j) * 2 + halfb) * 4) * 2;
    auto ldG = [&](int st) {
        int kk0 = st * 32;
        *(float4*)&aa[0] = *(const float4*)(asrc + kk0 + aq * 8);
        *(float4*)&aa[4] = *(const float4*)(asrc + kk0 + aq * 8 + 4);
        const s16x8* ph = (const s16x8*)(Ppk + (pbase + (size_t)st * 2 + 0) * 4096 + tid * 16);
        const s16x8* pl = (const s16x8*)(Ppk + (pbase + (size_t)st * 2 + 1) * 4096 + tid * 16);
        wh0 = ph[0]; wh1 = ph[1];
        wl0 = pl[0]; wl1 = pl[1];
    };
    ldG(0);
    for (int st = 0; st < 4; ++st) {
        __syncthreads();
        {
            s16x8 h, l; cvt_split8(aa, h, l);
            *(s16x8*)&Ah[arow][aq * 8] = h;
            *(s16x8*)&Al[arow][aq * 8] = l;
            *(s16x8*)&Wh[wcol][wkh * 16]     = wh0;
            *(s16x8*)&Wh[wcol][wkh * 16 + 8] = wh1;
            *(s16x8*)&Wl[wcol][wkh * 16]     = wl0;
            *(s16x8*)&Wl[wcol][wkh * 16 + 8] = wl1;
        }
        __syncthreads();
        if (st + 1 < 4) ldG(st + 1);
        s16x8 bh[2], bl[2];
        #pragma unroll
        for (int c = 0; c < 2; ++c) {
            int col = wv * 32 + c * 16 + lr;
            bh[c] = *(s16x8*)&Wh[col][lk];
            bl[c] = *(s16x8*)&Wl[col][lk];
        }
        s16x8 ppb_h, ppb_l;
        if (!halfb) {
            ppb_h = *(s16x8*)&PPh[lr][st * 32 + lk];
            ppb_l = *(s16x8*)&PPl[lr][st * 32 + lk];
        }
        #pragma unroll
        for (int mf = 0; mf < 4; ++mf) {
            s16x8 ah = *(s16x8*)&Ah[mf * 16 + lr][lk];
            s16x8 al = *(s16x8*)&Al[mf * 16 + lr][lk];
            #pragma unroll
            for (int c = 0; c < 2; ++c) {
                acc[mf][c] = __builtin_amdgcn_mfma_f32_16x16x32_bf16(ah, bh[c], acc[mf][c], 0, 0, 0);
                acc[mf][c] = __builtin_amdgcn_mfma_f32_16x16x32_bf16(ah, bl[c], acc[mf][c], 0, 0, 0);
                acc[mf][c] = __builtin_amdgcn_mfma_f32_16x16x32_bf16(al, bh[c], acc[mf][c], 0, 0, 0);
            }
            if (!halfb && (mf >> 1) == wv) {
                int i = mf & 1;
                acc_pp[i] = __builtin_amdgcn_mfma_f32_16x16x32_bf16(ah, ppb_h, acc_pp[i], 0, 0, 0);
                acc_pp[i] = __builtin_amdgcn_mfma_f32_16x16x32_bf16(ah, ppb_l, acc_pp[i], 0, 0, 0);
                acc_pp[i] = __builtin_amdgcn_mfma_f32_16x16x32_bf16(al, ppb_h, acc_pp[i], 0, 0, 0);
            }
        }
    }
    const float* pb = path_b + (size_t)(layer * J_ + j) * G_;
    float* outp = halfb ? XdB : Xs;
    const int rbase = (lane >> 4) * 4;
    #pragma unroll
    for (int mf = 0; mf < 4; ++mf) {
        #pragma unroll
        for (int c = 0; c < 2; ++c) {
            int col = wv * 32 + c * 16 + lr;
            float bias = halfb ? pb[col] : 0.f;
            #pragma unroll
            for (int rgi = 0; rgi < 4; ++rgi) {
                int row = row0 + mf * 16 + rbase + rgi;
                if (row < N_) outp[((size_t)layer * N_ + row) * G_ + col] = acc[mf][c][rgi] + bias;
            }
        }
    }
    if (!halfb) {
        #pragma unroll
        for (int i = 0; i < 2; ++i) {
            int mf = wv * 2 + i;
            #pragma unroll
            for (int rgi = 0; rgi < 4; ++rgi) {
                int row = row0 + mf * 16 + rbase + rgi;
                if (row >= N_) continue;
                float val = acc_pp[i][rgi];
                if (lr < 8) PS[((size_t)layer * N_ + row) * H_ + lr] = val;
                else        PDb[((size_t)layer * N_ + row) * H_ + (lr - 8)] = val + bAj[layer * H_ + (lr - 8)];
            }
        }
    }
}

// ---------------- fused per-(layer,node): logits+exp -> single-pass softmax-agg -> residual ----------------
__global__ __launch_bounds__(256) void k_node(
    const float* __restrict__ xcur, const float* __restrict__ Xs,
    const float* __restrict__ XdB, const float* __restrict__ Rlj,
    const float* __restrict__ PS, const float* __restrict__ PDb,
    const float* __restrict__ PRj,
    const int* __restrict__ cnt, const int2* __restrict__ csr_sl,
    float* __restrict__ xnext) {
    int l = blockIdx.x & 7;
    int n = (blockIdx.x >> 3) * 4 + (threadIdx.x >> 6);
    int lane = threadIdx.x & 63;
    int o0 = n * CAP_, o1 = o0 + cnt[n];
    const float* xr = xcur + ((size_t)l * N_ + n) * G_;
    float xv0 = xr[lane], xv1 = xr[lane + 64];
    float xd0 = XdB[((size_t)l * N_ + n) * G_ + lane];
    float xd1 = XdB[((size_t)l * N_ + n) * G_ + lane + 64];
    float out0, out1;
    if (o1 == o0) {
        out0 = fmaxf(xv0, 0.f);
        out1 = fmaxf(xv1, 0.f);
    } else {
        const int h0 = lane >> 4, h1 = h0 + 4;
        const float pd0 = PDb[((size_t)l * N_ + n) * H_ + h0];
        const float pd1 = PDb[((size_t)l * N_ + n) * H_ + h1];
        const float* PSl = PS + (size_t)l * N_ * H_;
        const float* PRl = PRj + (size_t)l * R_ * H_;
        const float* Xsl = Xs + (size_t)l * N_ * G_;
        const float* Rll = Rlj + (size_t)l * R_ * G_;
        float acc0 = 0.f, acc1 = 0.f, sum0 = 0.f, sum1 = 0.f;
        #pragma unroll 2
        for (int k = o0; k < o1; ++k) {
            int2 sl = csr_sl[k];
            float lg0 = PSl[sl.x * H_ + h0] + PRl[sl.y * H_ + h0] + pd0;
            float lg1 = PSl[sl.x * H_ + h1] + PRl[sl.y * H_ + h1] + pd1;
            lg0 = (lg0 >= 0.f) ? lg0 : 0.01f * lg0;
            lg1 = (lg1 >= 0.f) ? lg1 : 0.01f * lg1;
            float e0 = __expf(lg0), e1 = __expf(lg1);
            float v0 = Xsl[(size_t)sl.x * G_ + lane]      + Rll[(size_t)sl.y * G_ + lane];
            float v1 = Xsl[(size_t)sl.x * G_ + lane + 64] + Rll[(size_t)sl.y * G_ + lane + 64];
            acc0 += e0 * v0; sum0 += e0;
            acc1 += e1 * v1; sum1 += e1;
        }
        out0 = fmaxf(acc0 / sum0 + xd0 + xv0, 0.f);
        out1 = fmaxf(acc1 / sum1 + xd1 + xv1, 0.f);
    }
    float* dst = xnext + ((size_t)l * N_ + n) * G_;
    dst[lane] = out0;
    dst[lane + 64] = out1;
}

// ---------------- final: tanh(prefix) @ trans_w + b -> scatter pkv ----------------
// 160 blocks (layer x p x col-half), 1 output col per thread
__global__ __launch_bounds__(256) void k_out(
    const float* __restrict__ xfin, const int* __restrict__ imp_idx,
    const float* __restrict__ trans_w, const float* __restrict__ trans_b,
    float* __restrict__ out) {
    int blk = blockIdx.x;
    int layer = blk / (P_ * 2);
    int rem = blk % (P_ * 2);
    int p = rem >> 1;
    int half = rem & 1;
    __shared__ float th[G_];
    int t = threadIdx.x;
    int row = imp_idx[p];
    if (t < G_) th[t] = tanhf(xfin[((size_t)layer * N_ + row) * G_ + t]);
    __syncthreads();
    int c = half * 256 + t;
    float s = trans_b[layer * OUT2_ + c];
    const float* W = trans_w + (size_t)layer * G_ * OUT2_ + c;
    #pragma unroll 4
    for (int k = 0; k < G_; ++k) s += th[k] * W[(size_t)k * OUT2_];
    int c2 = c >> 8, kv = (c >> 5) & 7, oo = c & 31;
    for (int b = 0; b < B_; ++b) {
        out[(((((size_t)layer * 2 + c2) * B_ + b) * KV_ + kv) * P_ + p) * 32 + oo] = s;
    }
}

extern "C" void kernel_launch(void* const* d_in, const int* in_sizes, int n_in,
                              void* d_out, int out_size, void* d_ws, size_t ws_size,
                              hipStream_t stream) {
    const float* nft     = (const float*)d_in[0];
    const float* rft     = (const float*)d_in[1];
    const float* imp     = (const float*)d_in[2];
    const float* tg_w    = (const float*)d_in[3];
    const float* tg_b    = (const float*)d_in[4];
    const float* path_w  = (const float*)d_in[5];
    const float* path_b  = (const float*)d_in[6];
    const float* attn1_w = (const float*)d_in[7];
    const float* attn2_p = (const float*)d_in[8];
    const float* trans_w = (const float*)d_in[9];
    const float* trans_b = (const float*)d_in[10];
    // d_in[11] lamda: x = s*x + (1-s)*x is a no-op for any s
    const int* esrc = (const int*)d_in[12];
    const int* edst = (const int*)d_in[13];
    const int* elab = (const int*)d_in[14];
    float* out = (float*)d_out;

    char* w = (char*)d_ws;
    size_t off = 0;
    auto alloc = [&](size_t bytes) {
        void* p = w + off;
        off += (bytes + 255) & ~(size_t)255;
        return p;
    };
    float* x0      = (float*)alloc((size_t)L_ * N_ * G_ * 4);
    float* x1      = (float*)alloc((size_t)L_ * N_ * G_ * 4);
    float* rel     = (float*)alloc((size_t)L_ * R_ * G_ * 4);
    float* Xs      = (float*)alloc((size_t)L_ * N_ * G_ * 4);
    float* XdB     = (float*)alloc((size_t)L_ * N_ * G_ * 4);
    float* Rl      = (float*)alloc((size_t)J_ * L_ * R_ * G_ * 4);
    float* PS      = (float*)alloc((size_t)L_ * N_ * H_ * 4);
    float* PDb     = (float*)alloc((size_t)L_ * N_ * H_ * 4);
    float* PR      = (float*)alloc((size_t)J_ * L_ * R_ * H_ * 4);
    float* wPR     = (float*)alloc((size_t)J_ * L_ * H_ * G_ * 4);
    float* bA      = (float*)alloc((size_t)J_ * L_ * H_ * 4);
    short* Wpk     = (short*)alloc((size_t)L_ * 32 * 2 * 4096 * 2);
    short* Ppk     = (short*)alloc((size_t)L_ * J_ * 2 * 4 * 2 * 4096 * 2);
    short* PPk     = (short*)alloc((size_t)J_ * L_ * 2 * 2048 * 2);
    int*   cur     = (int*)alloc(N_ * 4);
    int2*  csr_sl  = (int2*)alloc((size_t)N_ * CAP_ * 8);
    int*   imp_idx = (int*)alloc(P_ * 4);

    // phase 0: tg_w repack (k_pre3's only dependency) + zero cur
    k_pre0<<<257, 256, 0, stream>>>(tg_w, Wpk, cur);
    // phase 1: pipelined tg GEMM || place || topk || psplit || prep
    //   (non-GEMM work rides the ~90% of CUs the GEMM leaves idle)
    k_pre3<<<520 + 250 + 1 + 192 + 96, 128, 0, stream>>>(
        nft, rft, Wpk, tg_b, x0, rel,
        edst, esrc, elab, imp, path_w, path_b, attn1_w, attn2_p,
        cur, csr_sl, imp_idx, Ppk, wPR, PPk, bA);

    float* xc = x0;
    float* xn = x1;
    for (int j = 0; j < J_; ++j) {
        int grid = (j == 0) ? (512 + J_ * L_ * 2) : 512;
        k_proj2<<<grid, 256, 0, stream>>>(
            xc, Ppk, PPk + (size_t)j * L_ * 2 * 2048, bA + (size_t)j * L_ * H_,
            path_b, j, Xs, XdB, PS, PDb,
            rel, path_w, wPR, Rl, PR);
        k_node<<<L_ * 500, 256, 0, stream>>>(
            xc, Xs, XdB, Rl + (size_t)j * L_ * R_ * G_, PS, PDb,
            PR + (size_t)j * L_ * R_ * H_,
            cur, csr_sl, xn);
        float* tmp = xc; xc = xn; xn = tmp;
    }
    k_out<<<L_ * P_ * 2, 256, 0, stream>>>(xc, imp_idx, trans_w, trans_b, out);
}